// Round 6
// baseline (294.751 us; speedup 1.0000x reference)
//
#include <hip/hip_runtime.h>
#include <math.h>
#include <float.h>

typedef __attribute__((ext_vector_type(4))) float f32x4;
typedef __attribute__((ext_vector_type(8))) __bf16 bf16x8;
typedef __attribute__((ext_vector_type(4))) __bf16 bf16x4;

#define NEG_TOPK 10
#define BROW 256      // batch rows, full per block
#define MT 64         // output cols per block
#define BK 64         // K-step
#define SIMSTR 72     // ushort stride for sims (144 B rows, 16B-aligned)
#define ABYTES 32768  // A tile bytes per step (256 rows x 128 B)
#define BUF 40960     // per staging buffer: A 32 KB + B 8 KB

// Branchless static-index top-k insert (sorted descending); pure VGPRs.
__device__ __forceinline__ void topk_ins(float (&top)[NEG_TOPK], float v) {
    #pragma unroll
    for (int q = NEG_TOPK - 1; q >= 1; --q)
        top[q] = fmaxf(fminf(v, top[q - 1]), top[q]);
    top[0] = fmaxf(top[0], v);
}

__device__ __forceinline__ bf16x4 cvt4(float4 v) {
    bf16x4 r;
    r[0] = (__bf16)v.x; r[1] = (__bf16)v.y;
    r[2] = (__bf16)v.z; r[3] = (__bf16)v.w;
    return r;
}

// Pass 0: convert A (fp32 [256][512]) -> bf16 in the INVERSE-SWIZZLED layout
// so pass1's linear global_load_lds reproduces the swizzled LDS image:
//   image[r*128 + ((g*8) ^ ((r&7)<<4))] = bf16x4(A[r][step*64 + g*4 ..])
__global__ __launch_bounds__(256) void cl_pass0(
    const float* __restrict__ A, char* __restrict__ A_swz, int D)
{
    const int idx = blockIdx.x * 256 + threadIdx.x;   // 32768 granules
    const int r    = idx >> 7;        // 0..255
    const int rem  = idx & 127;       // granule within row (8B = 4 bf16)
    const int step = rem >> 4;        // 0..7
    const int g    = rem & 15;        // 0..15
    float4 v = ((const float4*)A)[r * (D >> 2) + rem];
    bf16x4 b = cvt4(v);
    const int off = step * ABYTES + r * 128 + ((g * 8) ^ ((r & 7) << 4));
    *(unsigned long long*)(A_swz + off) = *(unsigned long long*)&b;
}

// Pass 1: bf16 MFMA GEMM, 256x64 tile, 8 waves (4x2) of 64x32 wave-tiles.
// A staged via global_load_lds_dwordx4 from pre-swizzled bf16 (zero VALU);
// B reg-staged 2 steps deep; one vmcnt(0)+barrier per K-step.
__global__ __launch_bounds__(512, 2) void cl_pass1(
    const char* __restrict__ A_swz, // [8][32768] pre-swizzled bf16 A tiles
    const float* __restrict__ Bm,   // [M, D]  inputs_row fp32
    const int* __restrict__ tcol,   // [256]
    const int* __restrict__ trow,   // [M]
    float* __restrict__ part_topk,  // [256, nch, 10]   nch = gridDim.x
    float* __restrict__ pos_part,   // [256, nch]
    int D)
{
    __shared__ char smem[2 * BUF];  // 80 KB -> 2 blocks/CU

    const int mb = blockIdx.x;
    const int j0 = mb * MT;
    const int t  = threadIdx.x;
    const int wave = t >> 6, lane = t & 63;
    const int wr = wave >> 1, wc = wave & 1;   // 4x2 waves; wave tile 64x32
    const int lrow = lane & 15, lk = lane >> 4;

    const float4* B4 = (const float4*)Bm;
    const int ldq = D >> 2;          // float4 per row
    const int NSTEP = D / BK;        // 8

    // B staging slices (64 rows x 16 f4 per step; 512 thr -> 2 f4 each)
    const int rb = t >> 4;           // row t>>4 + 32*s
    const int k4 = t & 15;

    f32x4 acc[4][2];
    #pragma unroll
    for (int m = 0; m < 4; ++m)
        #pragma unroll
        for (int n = 0; n < 2; ++n)
            acc[m][n] = (f32x4){0.f, 0.f, 0.f, 0.f};

    float4 brA[2], brB[2];           // two B prefetch sets (2-step deep)

    // per-wave A DMA addresses
    const char* gA = A_swz + wave * 4096 + lane * 16;
    char* lA0 = smem + wave * 4096;              // A region of buf0
    char* lA1 = smem + BUF + wave * 4096;        // A region of buf1

    // ---- prologue ----
    #pragma unroll
    for (int q = 0; q < 4; ++q)
        __builtin_amdgcn_global_load_lds(
            (const __attribute__((address_space(1))) void*)(gA + q * 1024),
            (__attribute__((address_space(3))) void*)(lA0 + q * 1024), 16, 0, 0);
    // B step0 -> setA, B step1 -> setB
    #pragma unroll
    for (int s = 0; s < 2; ++s)
        brA[s] = B4[(size_t)(j0 + rb + 32 * s) * ldq + 0 * (BK / 4) + k4];
    #pragma unroll
    for (int s = 0; s < 2; ++s)
        brB[s] = B4[(size_t)(j0 + rb + 32 * s) * ldq + 1 * (BK / 4) + k4];
    // stage B0 -> buf0
    {
        char* Bb = smem + ABYTES;
        #pragma unroll
        for (int s = 0; s < 2; ++s) {
            int r = rb + 32 * s;
            *(bf16x4*)(Bb + r * 128 + ((k4 * 8) ^ ((r & 7) << 4))) = cvt4(brA[s]);
        }
    }

    const int swz = (lrow & 7) << 4;

    for (int step = 0; step < NSTEP; ++step) {
        const int cur = step & 1;
        // drain this wave's outstanding vmem (incl. glds, no reg consumer)
        // and ds ops, then barrier. All loads were issued >= 1 compute phase
        // ago, so the drain is cheap; robust to scheduler reordering.
        asm volatile("s_waitcnt vmcnt(0) lgkmcnt(0)" ::: "memory");
        __builtin_amdgcn_s_barrier();

        // issue next A tile DMA, then B loads for step+2
        if (step + 1 < NSTEP) {
            const char* gp = gA + (step + 1) * ABYTES;
            char* lp = cur ? lA0 : lA1;
            #pragma unroll
            for (int q = 0; q < 4; ++q)
                __builtin_amdgcn_global_load_lds(
                    (const __attribute__((address_space(1))) void*)(gp + q * 1024),
                    (__attribute__((address_space(3))) void*)(lp + q * 1024), 16, 0, 0);
        }
        if (step + 2 < NSTEP) {
            const int kq = (step + 2) * (BK / 4);
            float4* dst = (step & 1) ? brB : brA;   // set (step+2)&1 == step&1
            #pragma unroll
            for (int s = 0; s < 2; ++s)
                dst[s] = B4[(size_t)(j0 + rb + 32 * s) * ldq + kq + k4];
        }

        // compute from buf[cur]
        {
            const char* Ab = smem + cur * BUF;
            const char* Bb = Ab + ABYTES;
            #pragma unroll
            for (int ks = 0; ks < 2; ++ks) {
                bf16x8 af[4], bfr[2];
                const int kb = ks * 64 + lk * 16;
                #pragma unroll
                for (int m = 0; m < 4; ++m) {
                    int row = wr * 64 + m * 16 + lrow;
                    af[m] = *(const bf16x8*)(Ab + row * 128 + (kb ^ swz));
                }
                #pragma unroll
                for (int n = 0; n < 2; ++n) {
                    int row = wc * 32 + n * 16 + lrow;
                    bfr[n] = *(const bf16x8*)(Bb + row * 128 + (kb ^ swz));
                }
                #pragma unroll
                for (int m = 0; m < 4; ++m)
                    #pragma unroll
                    for (int n = 0; n < 2; ++n)
                        acc[m][n] = __builtin_amdgcn_mfma_f32_16x16x32_bf16(
                            af[m], bfr[n], acc[m][n], 0, 0, 0);
            }
        }

        // stage B(step+1) -> buf[cur^1] from set (step+1)&1 (loaded last iter;
        // compiler inserts the register-dependency vmcnt wait automatically)
        if (step + 1 < NSTEP) {
            char* Bb = smem + (cur ^ 1) * BUF + ABYTES;
            const float4* src = (step & 1) ? brA : brB;
            #pragma unroll
            for (int s = 0; s < 2; ++s) {
                int r = rb + 32 * s;
                *(bf16x4*)(Bb + r * 128 + ((k4 * 8) ^ ((r & 7) << 4))) = cvt4(src[s]);
            }
        }
    }

    // ---- epilogue: sims (bf16 [256][72]) into buf0 region (disjoint from
    // buf1 which the last step read; all waves passed the final barrier)
    unsigned short* simsb = (unsigned short*)smem;
    #pragma unroll
    for (int m = 0; m < 4; ++m)
        #pragma unroll
        for (int n = 0; n < 2; ++n)
            #pragma unroll
            for (int r = 0; r < 4; ++r) {
                int row = wr * 64 + m * 16 + lk * 4 + r;
                int col = wc * 32 + n * 16 + lrow;
                __bf16 b = (__bf16)acc[m][n][r];
                simsb[row * SIMSTR + col] = *(unsigned short*)&b;
            }
    __syncthreads();

    // fused scan: 2 threads per row, 32 cols each; labels straight from global
    {
        const int row = t >> 1, half = t & 1;
        const int myc = tcol[row];
        const int4* lab4 = (const int4*)(trow + j0 + half * 32);
        float top[NEG_TOPK];
        #pragma unroll
        for (int q = 0; q < NEG_TOPK; ++q) top[q] = -INFINITY;
        float pos = 0.f;
        #pragma unroll
        for (int j = 0; j < 4; ++j) {
            bf16x8 v8 = *(const bf16x8*)(&simsb[row * SIMSTR + half * 32 + j * 8]);
            int4 l1 = lab4[2 * j], l2 = lab4[2 * j + 1];
            int lab[8] = {l1.x, l1.y, l1.z, l1.w, l2.x, l2.y, l2.z, l2.w};
            #pragma unroll
            for (int e = 0; e < 8; ++e) {
                float s = (float)v8[e];
                bool same = (lab[e] == myc);
                pos += (same && s < 0.99999f) ? (1.f - s) : 0.f;
                topk_ins(top, same ? -INFINITY : s);
            }
        }
        // pair-merge via buf1 region (free now)
        float* mtop = (float*)(smem + BUF);            // [512][10]
        float* mpos = (float*)(smem + BUF + 20480);    // [512]
        #pragma unroll
        for (int q = 0; q < NEG_TOPK; ++q) mtop[t * NEG_TOPK + q] = top[q];
        mpos[t] = pos;
        __syncthreads();
        if (half == 0) {
            const float* ot = &mtop[(t + 1) * NEG_TOPK];
            #pragma unroll
            for (int q = 0; q < NEG_TOPK; ++q) topk_ins(top, ot[q]);
            float post = pos + mpos[t + 1];
            float* dst = part_topk + ((size_t)row * gridDim.x + mb) * NEG_TOPK;
            #pragma unroll
            for (int q = 0; q < NEG_TOPK; ++q) dst[q] = top[q];
            pos_part[(size_t)row * gridDim.x + mb] = post;
        }
    }
}

// Pass 2: one block per row. Merge nch*10 candidates -> top-10, sum finite;
// reduce pos partials; row_tot[i] = pos + neg.
__global__ __launch_bounds__(256) void cl_pass2(
    const float* __restrict__ part_topk,
    const float* __restrict__ pos_part,
    float* __restrict__ row_tot,
    int nch)
{
    const int i = blockIdx.x;
    const int t = threadIdx.x;
    __shared__ float stop[256][NEG_TOPK];
    __shared__ float stop2[32][NEG_TOPK];
    __shared__ float red[256];

    const int n = nch * NEG_TOPK;
    const float* src = part_topk + (size_t)i * n;
    float top[NEG_TOPK];
    #pragma unroll
    for (int q = 0; q < NEG_TOPK; ++q) top[q] = -INFINITY;
    for (int idx = t; idx < n; idx += 256) topk_ins(top, src[idx]);
    #pragma unroll
    for (int q = 0; q < NEG_TOPK; ++q) stop[t][q] = top[q];

    float pos = 0.0f;
    const float* psrc = pos_part + (size_t)i * nch;
    for (int idx = t; idx < nch; idx += 256) pos += psrc[idx];
    red[t] = pos;
    __syncthreads();

    for (int s2 = 128; s2 >= 1; s2 >>= 1) {
        if (t < s2) red[t] += red[t + s2];
        __syncthreads();
    }

    if (t < 32) {
        float m[NEG_TOPK];
        #pragma unroll
        for (int q = 0; q < NEG_TOPK; ++q) m[q] = -INFINITY;
        for (int l = 0; l < 8; ++l)
            #pragma unroll
            for (int q = 0; q < NEG_TOPK; ++q) topk_ins(m, stop[t * 8 + l][q]);
        #pragma unroll
        for (int q = 0; q < NEG_TOPK; ++q) stop2[t][q] = m[q];
    }
    __syncthreads();

    if (t == 0) {
        float m[NEG_TOPK];
        #pragma unroll
        for (int q = 0; q < NEG_TOPK; ++q) m[q] = -INFINITY;
        for (int l = 0; l < 32; ++l)
            #pragma unroll
            for (int q = 0; q < NEG_TOPK; ++q) topk_ins(m, stop2[l][q]);
        float neg = 0.0f;
        #pragma unroll
        for (int q = 0; q < NEG_TOPK; ++q)
            if (isfinite(m[q])) neg += m[q];
        row_tot[i] = neg + red[0];
    }
}

// Pass 3: mean over rows.
__global__ __launch_bounds__(256) void cl_pass3(
    const float* __restrict__ row_tot, float* __restrict__ out, int Bn)
{
    __shared__ float red[256];
    const int t = threadIdx.x;
    float v = 0.0f;
    for (int idx = t; idx < Bn; idx += 256) v += row_tot[idx];
    red[t] = v;
    __syncthreads();
    for (int s2 = 128; s2 >= 1; s2 >>= 1) {
        if (t < s2) red[t] += red[t + s2];
        __syncthreads();
    }
    if (t == 0) out[0] = red[0] / (float)Bn;
}

extern "C" void kernel_launch(void* const* d_in, const int* in_sizes, int n_in,
                              void* d_out, int out_size, void* d_ws, size_t ws_size,
                              hipStream_t stream)
{
    const float* A    = (const float*)d_in[0];  // inputs_col [B,D]
    const int*   tcol = (const int*)d_in[1];    // targets_col [B]
    const float* Bm   = (const float*)d_in[2];  // inputs_row [M,D]
    const int*   trow = (const int*)d_in[3];    // target_row [M]
    float* out = (float*)d_out;

    const int Bn = in_sizes[1];          // 256
    const int M  = in_sizes[3];          // 65536
    const int D  = in_sizes[0] / Bn;     // 512
    const int numMB = M / MT;            // 1024 blocks = chunks
    const int nch = numMB;

    char* A_swz = (char*)d_ws;                                    // 256 KB
    float* part_topk = (float*)(A_swz + 8 * ABYTES);              // B*nch*10
    float* pos_part  = part_topk + (size_t)Bn * nch * NEG_TOPK;   // B*nch
    float* row_tot   = pos_part + (size_t)Bn * nch;               // B

    cl_pass0<<<128, 256, 0, stream>>>(A, A_swz, D);
    cl_pass1<<<numMB, 512, 0, stream>>>(A_swz, Bm, tcol, trow,
                                        part_topk, pos_part, D);
    cl_pass2<<<Bn, 256, 0, stream>>>(part_topk, pos_part, row_tot, nch);
    cl_pass3<<<1, 256, 0, stream>>>(row_tot, out, Bn);
}

// Round 7
// 255.375 us; speedup vs baseline: 1.1542x; 1.1542x over previous
//
#include <hip/hip_runtime.h>
#include <math.h>
#include <float.h>

typedef __attribute__((ext_vector_type(4))) float f32x4;
typedef __attribute__((ext_vector_type(8))) __bf16 bf16x8;
typedef __attribute__((ext_vector_type(4))) __bf16 bf16x4;

#define NEG_TOPK 10
#define BROW 256      // batch rows, full per block
#define MT 64         // output cols per block
#define BK 64         // K-step
#define SIMSTR 72     // ushort stride for sims (144 B rows, 16B-aligned)
#define ABYTES 32768  // A tile bytes per step (256 rows x 128 B)
#define BUF 40960     // per staging buffer: A 32 KB + B 8 KB

// Branchless static-index top-k insert (sorted descending); pure VGPRs.
__device__ __forceinline__ void topk_ins(float (&top)[NEG_TOPK], float v) {
    #pragma unroll
    for (int q = NEG_TOPK - 1; q >= 1; --q)
        top[q] = fmaxf(fminf(v, top[q - 1]), top[q]);
    top[0] = fmaxf(top[0], v);
}

__device__ __forceinline__ bf16x4 cvt4(float4 v) {
    bf16x4 r;
    r[0] = (__bf16)v.x; r[1] = (__bf16)v.y;
    r[2] = (__bf16)v.z; r[3] = (__bf16)v.w;
    return r;
}

// Pass 0: convert A (fp32 [256][512]) -> bf16 in the INVERSE-SWIZZLED layout
// so pass1's linear global_load_lds reproduces the swizzled LDS image:
//   image[r*128 + ((g*8) ^ ((r&7)<<4))] = bf16x4(A[r][step*64 + g*4 ..])
__global__ __launch_bounds__(256) void cl_pass0(
    const float* __restrict__ A, char* __restrict__ A_swz, int D)
{
    const int idx = blockIdx.x * 256 + threadIdx.x;   // 32768 granules
    const int r    = idx >> 7;        // 0..255
    const int rem  = idx & 127;       // granule within row (8B = 4 bf16)
    const int step = rem >> 4;        // 0..7
    const int g    = rem & 15;        // 0..15
    float4 v = ((const float4*)A)[r * (D >> 2) + rem];
    bf16x4 b = cvt4(v);
    const int off = step * ABYTES + r * 128 + ((g * 8) ^ ((r & 7) << 4));
    *(unsigned long long*)(A_swz + off) = *(unsigned long long*)&b;
}

// Pass 1: bf16 MFMA GEMM, 256x64 tile, 8 waves (4x2) of 64x32 wave-tiles.
// A staged via global_load_lds_dwordx4 from pre-swizzled bf16 (zero VALU);
// B reg-staged 2 steps deep with STATIC register-set names (even/odd paired
// loop — rule #20: no runtime-selected pointers to register arrays).
__global__ __launch_bounds__(512, 2) void cl_pass1(
    const char* __restrict__ A_swz, // [8][32768] pre-swizzled bf16 A tiles
    const float* __restrict__ Bm,   // [M, D]  inputs_row fp32
    const int* __restrict__ tcol,   // [256]
    const int* __restrict__ trow,   // [M]
    float* __restrict__ part_topk,  // [256, nch, 10]   nch = gridDim.x
    float* __restrict__ pos_part,   // [256, nch]
    int D)
{
    __shared__ char smem[2 * BUF];  // 80 KB -> 2 blocks/CU

    const int mb = blockIdx.x;
    const int j0 = mb * MT;
    const int t  = threadIdx.x;
    const int wave = t >> 6, lane = t & 63;
    const int wr = wave >> 1, wc = wave & 1;   // 4x2 waves; wave tile 64x32
    const int lrow = lane & 15, lk = lane >> 4;

    const float4* B4 = (const float4*)Bm;
    const int ldq = D >> 2;          // float4 per row
    const int NSTEP = D / BK;        // 8

    // B staging slices (64 rows x 16 f4 per step; 512 thr -> 2 f4 each)
    const int rb = t >> 4;           // row t>>4 + 32*s
    const int k4 = t & 15;

    f32x4 acc[4][2];
    #pragma unroll
    for (int m = 0; m < 4; ++m)
        #pragma unroll
        for (int n = 0; n < 2; ++n)
            acc[m][n] = (f32x4){0.f, 0.f, 0.f, 0.f};

    float4 brA[2], brB[2];           // two B prefetch sets, statically named

    // per-wave A DMA addresses
    const char* gA = A_swz + wave * 4096 + lane * 16;
    char* lA0 = smem + wave * 4096;              // A region of buf0
    char* lA1 = smem + BUF + wave * 4096;        // A region of buf1

    const int swz = (lrow & 7) << 4;

#define GLDS_A(STEP, LP)                                                       \
    {                                                                          \
        const char* gp_ = gA + (STEP) * ABYTES;                                \
        _Pragma("unroll")                                                      \
        for (int q = 0; q < 4; ++q)                                            \
            __builtin_amdgcn_global_load_lds(                                  \
                (const __attribute__((address_space(1))) void*)(gp_ + q*1024), \
                (__attribute__((address_space(3))) void*)((LP) + q*1024),      \
                16, 0, 0);                                                     \
    }

#define LOAD_B(STEP, SET)                                                      \
    {                                                                          \
        const int kq_ = (STEP) * (BK / 4);                                     \
        _Pragma("unroll")                                                      \
        for (int s = 0; s < 2; ++s)                                            \
            SET[s] = B4[(size_t)(j0 + rb + 32 * s) * ldq + kq_ + k4];          \
    }

#define STAGE_B(BUFP, SET)                                                     \
    {                                                                          \
        char* Bb_ = (BUFP) + ABYTES;                                           \
        _Pragma("unroll")                                                      \
        for (int s = 0; s < 2; ++s) {                                          \
            int r_ = rb + 32 * s;                                              \
            *(bf16x4*)(Bb_ + r_ * 128 + ((k4 * 8) ^ ((r_ & 7) << 4))) =        \
                cvt4(SET[s]);                                                  \
        }                                                                      \
    }

#define COMPUTE(BUFP)                                                          \
    {                                                                          \
        const char* Ab_ = (BUFP);                                              \
        const char* Bb_ = Ab_ + ABYTES;                                        \
        _Pragma("unroll")                                                      \
        for (int ks = 0; ks < 2; ++ks) {                                       \
            bf16x8 af[4], bfr[2];                                              \
            const int kb_ = ks * 64 + lk * 16;                                 \
            _Pragma("unroll")                                                  \
            for (int m = 0; m < 4; ++m) {                                      \
                int row_ = wr * 64 + m * 16 + lrow;                            \
                af[m] = *(const bf16x8*)(Ab_ + row_ * 128 + (kb_ ^ swz));      \
            }                                                                  \
            _Pragma("unroll")                                                  \
            for (int n = 0; n < 2; ++n) {                                      \
                int row_ = wc * 32 + n * 16 + lrow;                            \
                bfr[n] = *(const bf16x8*)(Bb_ + row_ * 128 + (kb_ ^ swz));     \
            }                                                                  \
            _Pragma("unroll")                                                  \
            for (int m = 0; m < 4; ++m)                                        \
                _Pragma("unroll")                                              \
                for (int n = 0; n < 2; ++n)                                    \
                    acc[m][n] = __builtin_amdgcn_mfma_f32_16x16x32_bf16(       \
                        af[m], bfr[n], acc[m][n], 0, 0, 0);                    \
        }                                                                      \
    }

#define DRAIN_BARRIER()                                                        \
    asm volatile("s_waitcnt vmcnt(0) lgkmcnt(0)" ::: "memory");                \
    __builtin_amdgcn_s_barrier();

    // ---- prologue ----
    GLDS_A(0, lA0);
    LOAD_B(0, brA);
    LOAD_B(1, brB);
    STAGE_B(smem, brA);   // B0 -> buf0 (compiler waits on brA regs)

    // ---- paired main loop: even sub-step uses buf0/brA, odd uses buf1/brB
    for (int step = 0; step < NSTEP; step += 2) {
        // even sub-step (cur = buf0)
        DRAIN_BARRIER();
        if (step + 1 < NSTEP) GLDS_A(step + 1, lA1);
        if (step + 2 < NSTEP) LOAD_B(step + 2, brA);
        COMPUTE(smem);
        if (step + 1 < NSTEP) STAGE_B(smem + BUF, brB);

        // odd sub-step (cur = buf1)
        if (step + 1 < NSTEP) {
            DRAIN_BARRIER();
            if (step + 2 < NSTEP) GLDS_A(step + 2, lA0);
            if (step + 3 < NSTEP) LOAD_B(step + 3, brB);
            COMPUTE(smem + BUF);
            if (step + 2 < NSTEP) STAGE_B(smem, brA);
        }
    }
    DRAIN_BARRIER();   // final: all LDS ops / stray vmem done before epilogue

    // ---- epilogue: sims (bf16 [256][72]) into buf0 region
    unsigned short* simsb = (unsigned short*)smem;
    #pragma unroll
    for (int m = 0; m < 4; ++m)
        #pragma unroll
        for (int n = 0; n < 2; ++n)
            #pragma unroll
            for (int r = 0; r < 4; ++r) {
                int row = wr * 64 + m * 16 + lk * 4 + r;
                int col = wc * 32 + n * 16 + lrow;
                __bf16 b = (__bf16)acc[m][n][r];
                simsb[row * SIMSTR + col] = *(unsigned short*)&b;
            }
    __syncthreads();

    // fused scan: 2 threads per row, 32 cols each; labels straight from global
    {
        const int row = t >> 1, half = t & 1;
        const int myc = tcol[row];
        const int4* lab4 = (const int4*)(trow + j0 + half * 32);
        float top[NEG_TOPK];
        #pragma unroll
        for (int q = 0; q < NEG_TOPK; ++q) top[q] = -INFINITY;
        float pos = 0.f;
        #pragma unroll
        for (int j = 0; j < 4; ++j) {
            bf16x8 v8 = *(const bf16x8*)(&simsb[row * SIMSTR + half * 32 + j * 8]);
            int4 l1 = lab4[2 * j], l2 = lab4[2 * j + 1];
            int lab[8] = {l1.x, l1.y, l1.z, l1.w, l2.x, l2.y, l2.z, l2.w};
            #pragma unroll
            for (int e = 0; e < 8; ++e) {
                float s = (float)v8[e];
                bool same = (lab[e] == myc);
                pos += (same && s < 0.99999f) ? (1.f - s) : 0.f;
                topk_ins(top, same ? -INFINITY : s);
            }
        }
        // pair-merge via buf1 region (free now)
        float* mtop = (float*)(smem + BUF);            // [512][10]
        float* mpos = (float*)(smem + BUF + 20480);    // [512]
        #pragma unroll
        for (int q = 0; q < NEG_TOPK; ++q) mtop[t * NEG_TOPK + q] = top[q];
        mpos[t] = pos;
        __syncthreads();
        if (half == 0) {
            const float* ot = &mtop[(t + 1) * NEG_TOPK];
            #pragma unroll
            for (int q = 0; q < NEG_TOPK; ++q) topk_ins(top, ot[q]);
            float post = pos + mpos[t + 1];
            float* dst = part_topk + ((size_t)row * gridDim.x + mb) * NEG_TOPK;
            #pragma unroll
            for (int q = 0; q < NEG_TOPK; ++q) dst[q] = top[q];
            pos_part[(size_t)row * gridDim.x + mb] = post;
        }
    }
}

// Pass 2: one block per row. Merge nch*10 candidates -> top-10, sum finite;
// reduce pos partials; row_tot[i] = pos + neg.
__global__ __launch_bounds__(256) void cl_pass2(
    const float* __restrict__ part_topk,
    const float* __restrict__ pos_part,
    float* __restrict__ row_tot,
    int nch)
{
    const int i = blockIdx.x;
    const int t = threadIdx.x;
    __shared__ float stop[256][NEG_TOPK];
    __shared__ float stop2[32][NEG_TOPK];
    __shared__ float red[256];

    const int n = nch * NEG_TOPK;
    const float* src = part_topk + (size_t)i * n;
    float top[NEG_TOPK];
    #pragma unroll
    for (int q = 0; q < NEG_TOPK; ++q) top[q] = -INFINITY;
    for (int idx = t; idx < n; idx += 256) topk_ins(top, src[idx]);
    #pragma unroll
    for (int q = 0; q < NEG_TOPK; ++q) stop[t][q] = top[q];

    float pos = 0.0f;
    const float* psrc = pos_part + (size_t)i * nch;
    for (int idx = t; idx < nch; idx += 256) pos += psrc[idx];
    red[t] = pos;
    __syncthreads();

    for (int s2 = 128; s2 >= 1; s2 >>= 1) {
        if (t < s2) red[t] += red[t + s2];
        __syncthreads();
    }

    if (t < 32) {
        float m[NEG_TOPK];
        #pragma unroll
        for (int q = 0; q < NEG_TOPK; ++q) m[q] = -INFINITY;
        for (int l = 0; l < 8; ++l)
            #pragma unroll
            for (int q = 0; q < NEG_TOPK; ++q) topk_ins(m, stop[t * 8 + l][q]);
        #pragma unroll
        for (int q = 0; q < NEG_TOPK; ++q) stop2[t][q] = m[q];
    }
    __syncthreads();

    if (t == 0) {
        float m[NEG_TOPK];
        #pragma unroll
        for (int q = 0; q < NEG_TOPK; ++q) m[q] = -INFINITY;
        for (int l = 0; l < 32; ++l)
            #pragma unroll
            for (int q = 0; q < NEG_TOPK; ++q) topk_ins(m, stop2[l][q]);
        float neg = 0.0f;
        #pragma unroll
        for (int q = 0; q < NEG_TOPK; ++q)
            if (isfinite(m[q])) neg += m[q];
        row_tot[i] = neg + red[0];
    }
}

// Pass 3: mean over rows.
__global__ __launch_bounds__(256) void cl_pass3(
    const float* __restrict__ row_tot, float* __restrict__ out, int Bn)
{
    __shared__ float red[256];
    const int t = threadIdx.x;
    float v = 0.0f;
    for (int idx = t; idx < Bn; idx += 256) v += row_tot[idx];
    red[t] = v;
    __syncthreads();
    for (int s2 = 128; s2 >= 1; s2 >>= 1) {
        if (t < s2) red[t] += red[t + s2];
        __syncthreads();
    }
    if (t == 0) out[0] = red[0] / (float)Bn;
}

extern "C" void kernel_launch(void* const* d_in, const int* in_sizes, int n_in,
                              void* d_out, int out_size, void* d_ws, size_t ws_size,
                              hipStream_t stream)
{
    const float* A    = (const float*)d_in[0];  // inputs_col [B,D]
    const int*   tcol = (const int*)d_in[1];    // targets_col [B]
    const float* Bm   = (const float*)d_in[2];  // inputs_row [M,D]
    const int*   trow = (const int*)d_in[3];    // target_row [M]
    float* out = (float*)d_out;

    const int Bn = in_sizes[1];          // 256
    const int M  = in_sizes[3];          // 65536
    const int D  = in_sizes[0] / Bn;     // 512
    const int numMB = M / MT;            // 1024 blocks = chunks
    const int nch = numMB;

    char* A_swz = (char*)d_ws;                                    // 256 KB
    float* part_topk = (float*)(A_swz + 8 * ABYTES);              // B*nch*10
    float* pos_part  = part_topk + (size_t)Bn * nch * NEG_TOPK;   // B*nch
    float* row_tot   = pos_part + (size_t)Bn * nch;               // B

    cl_pass0<<<128, 256, 0, stream>>>(A, A_swz, D);
    cl_pass1<<<numMB, 512, 0, stream>>>(A_swz, Bm, tcol, trow,
                                        part_topk, pos_part, D);
    cl_pass2<<<Bn, 256, 0, stream>>>(part_topk, pos_part, row_tot, nch);
    cl_pass3<<<1, 256, 0, stream>>>(row_tot, out, Bn);
}

// Round 8
// 254.724 us; speedup vs baseline: 1.1571x; 1.0026x over previous
//
#include <hip/hip_runtime.h>
#include <math.h>
#include <float.h>

typedef __attribute__((ext_vector_type(4))) float f32x4;
typedef __attribute__((ext_vector_type(8))) __bf16 bf16x8;
typedef __attribute__((ext_vector_type(4))) __bf16 bf16x4;

#define NEG_TOPK 10
#define BROW 256      // batch rows, full per block
#define MT 64         // output cols per block
#define BK 64         // K-step
#define SIMSTR 72     // ushort stride for sims (144 B rows, 16B-aligned)
#define ABYTES 32768  // A tile bytes per step (256 rows x 128 B)
#define BUF 40960     // per staging buffer: A 32 KB + B 8 KB

// Branchless static-index top-k insert (sorted descending); pure VGPRs.
__device__ __forceinline__ void topk_ins(float (&top)[NEG_TOPK], float v) {
    #pragma unroll
    for (int q = NEG_TOPK - 1; q >= 1; --q)
        top[q] = fmaxf(fminf(v, top[q - 1]), top[q]);
    top[0] = fmaxf(top[0], v);
}

__device__ __forceinline__ bf16x4 cvt4(float4 v) {
    bf16x4 r;
    r[0] = (__bf16)v.x; r[1] = (__bf16)v.y;
    r[2] = (__bf16)v.z; r[3] = (__bf16)v.w;
    return r;
}

// Pass 0: convert A (fp32 [256][512]) -> bf16 in the INVERSE-SWIZZLED layout
// so pass1's linear global_load_lds reproduces the swizzled LDS image:
//   image[r*128 + ((g*8) ^ ((r&7)<<4))] = bf16x4(A[r][step*64 + g*4 ..])
__global__ __launch_bounds__(256) void cl_pass0(
    const float* __restrict__ A, char* __restrict__ A_swz, int D)
{
    const int idx = blockIdx.x * 256 + threadIdx.x;   // 32768 granules
    const int r    = idx >> 7;        // 0..255
    const int rem  = idx & 127;       // granule within row (8B = 4 bf16)
    const int step = rem >> 4;        // 0..7
    const int g    = rem & 15;        // 0..15
    float4 v = ((const float4*)A)[r * (D >> 2) + rem];
    bf16x4 b = cvt4(v);
    const int off = step * ABYTES + r * 128 + ((g * 8) ^ ((r & 7) << 4));
    *(unsigned long long*)(A_swz + off) = *(unsigned long long*)&b;
}

// Pass 1: bf16 MFMA GEMM, 256x64 tile, 8 waves (4x2) of 64x32 wave-tiles.
// A staged via global_load_lds_dwordx4 from pre-swizzled bf16 (zero VALU);
// B reg-staged 2 steps deep (static even/odd register sets); COUNTED vmcnt
// barrier (T4): drain only the glds (4 oldest), keep B prefetch in flight.
__global__ __launch_bounds__(512, 2) void cl_pass1(
    const char* __restrict__ A_swz, // [8][32768] pre-swizzled bf16 A tiles
    const float* __restrict__ Bm,   // [M, D]  inputs_row fp32
    const int* __restrict__ tcol,   // [256]
    const int* __restrict__ trow,   // [M]
    float* __restrict__ part_topk,  // [256, nch, 10]   nch = gridDim.x
    float* __restrict__ pos_part,   // [256, nch]
    int D)
{
    __shared__ char smem[2 * BUF];  // 80 KB -> 2 blocks/CU

    const int mb = blockIdx.x;
    const int j0 = mb * MT;
    const int t  = threadIdx.x;
    const int wave = t >> 6, lane = t & 63;
    const int wr = wave >> 1, wc = wave & 1;   // 4x2 waves; wave tile 64x32
    const int lrow = lane & 15, lk = lane >> 4;

    const float4* B4 = (const float4*)Bm;
    const int ldq = D >> 2;          // float4 per row
    const int NSTEP = D / BK;        // 8

    // B staging slices (64 rows x 16 f4 per step; 512 thr -> 2 f4 each)
    const int rb = t >> 4;           // row t>>4 + 32*s
    const int k4 = t & 15;

    f32x4 acc[4][2];
    #pragma unroll
    for (int m = 0; m < 4; ++m)
        #pragma unroll
        for (int n = 0; n < 2; ++n)
            acc[m][n] = (f32x4){0.f, 0.f, 0.f, 0.f};

    float4 brA[2], brB[2];           // two B prefetch sets, statically named

    // per-wave A DMA addresses
    const char* gA = A_swz + wave * 4096 + lane * 16;
    char* lA0 = smem + wave * 4096;              // A region of buf0
    char* lA1 = smem + BUF + wave * 4096;        // A region of buf1

    const int swz = (lrow & 7) << 4;

// glds group, then a sched barrier so nothing is scheduled above/between —
// the 4 glds must stay the OLDEST vmem ops for the counted wait to be exact.
#define GLDS_A(STEP, LP)                                                       \
    {                                                                          \
        const char* gp_ = gA + (STEP) * ABYTES;                                \
        _Pragma("unroll")                                                      \
        for (int q = 0; q < 4; ++q)                                            \
            __builtin_amdgcn_global_load_lds(                                  \
                (const __attribute__((address_space(1))) void*)(gp_ + q*1024), \
                (__attribute__((address_space(3))) void*)((LP) + q*1024),      \
                16, 0, 0);                                                     \
        __builtin_amdgcn_sched_barrier(0);                                     \
    }

#define LOAD_B(STEP, SET)                                                      \
    {                                                                          \
        const int kq_ = (STEP) * (BK / 4);                                     \
        _Pragma("unroll")                                                      \
        for (int s = 0; s < 2; ++s)                                            \
            SET[s] = B4[(size_t)(j0 + rb + 32 * s) * ldq + kq_ + k4];          \
        __builtin_amdgcn_sched_barrier(0);                                     \
    }

#define STAGE_B(BUFP, SET)                                                     \
    {                                                                          \
        char* Bb_ = (BUFP) + ABYTES;                                           \
        _Pragma("unroll")                                                      \
        for (int s = 0; s < 2; ++s) {                                          \
            int r_ = rb + 32 * s;                                              \
            *(bf16x4*)(Bb_ + r_ * 128 + ((k4 * 8) ^ ((r_ & 7) << 4))) =        \
                cvt4(SET[s]);                                                  \
        }                                                                      \
    }

#define COMPUTE(BUFP)                                                          \
    {                                                                          \
        const char* Ab_ = (BUFP);                                              \
        const char* Bb_ = Ab_ + ABYTES;                                        \
        _Pragma("unroll")                                                      \
        for (int ks = 0; ks < 2; ++ks) {                                       \
            bf16x8 af[4], bfr[2];                                              \
            const int kb_ = ks * 64 + lk * 16;                                 \
            _Pragma("unroll")                                                  \
            for (int m = 0; m < 4; ++m) {                                      \
                int row_ = wr * 64 + m * 16 + lrow;                            \
                af[m] = *(const bf16x8*)(Ab_ + row_ * 128 + (kb_ ^ swz));      \
            }                                                                  \
            _Pragma("unroll")                                                  \
            for (int n = 0; n < 2; ++n) {                                      \
                int row_ = wc * 32 + n * 16 + lrow;                            \
                bfr[n] = *(const bf16x8*)(Bb_ + row_ * 128 + (kb_ ^ swz));     \
            }                                                                  \
            _Pragma("unroll")                                                  \
            for (int m = 0; m < 4; ++m)                                        \
                _Pragma("unroll")                                              \
                for (int n = 0; n < 2; ++n)                                    \
                    acc[m][n] = __builtin_amdgcn_mfma_f32_16x16x32_bf16(       \
                        af[m], bfr[n], acc[m][n], 0, 0, 0);                    \
        }                                                                      \
    }

// Counted barrier. CNT=2: waits only the 4 oldest vmem (the glds issued one
// full step ago); the 2 youngest (B prefetch) stay in flight across the
// barrier. CNT=0 ONLY at the last step, where the queue holds just the 4
// glds and vmcnt(2) would under-wait (stale A tile). lgkmcnt(0) makes this
// wave's STAGE_B ds_writes visible; sched_barrier keeps ds_reads below.
#define DRAIN_BARRIER(CNT)                                                     \
    asm volatile("s_waitcnt vmcnt(" #CNT ") lgkmcnt(0)" ::: "memory");         \
    __builtin_amdgcn_s_barrier();                                              \
    __builtin_amdgcn_sched_barrier(0);

    // ---- prologue ----
    GLDS_A(0, lA0);
    LOAD_B(0, brA);
    LOAD_B(1, brB);
    STAGE_B(smem, brA);   // implicit vmcnt(2) wait on brA -> glds0 also done

    // ---- paired main loop: even sub-step uses buf0/brA, odd uses buf1/brB
    for (int step = 0; step < NSTEP; step += 2) {
        // even sub-step (cur = buf0)
        if (step < NSTEP - 1) { DRAIN_BARRIER(2) } else { DRAIN_BARRIER(0) }
        if (step + 1 < NSTEP) GLDS_A(step + 1, lA1);
        if (step + 2 < NSTEP) LOAD_B(step + 2, brA);
        COMPUTE(smem);
        if (step + 1 < NSTEP) STAGE_B(smem + BUF, brB);

        // odd sub-step (cur = buf1)
        if (step + 1 < NSTEP) {
            if (step + 1 < NSTEP - 1) { DRAIN_BARRIER(2) } else { DRAIN_BARRIER(0) }
            if (step + 2 < NSTEP) GLDS_A(step + 2, lA0);
            if (step + 3 < NSTEP) LOAD_B(step + 3, brB);
            COMPUTE(smem + BUF);
            if (step + 2 < NSTEP) STAGE_B(smem, brA);
        }
    }
    DRAIN_BARRIER(0)   // all LDS ops / stray vmem done before epilogue reuse

    // ---- epilogue: sims (bf16 [256][72]) into buf0 region
    unsigned short* simsb = (unsigned short*)smem;
    #pragma unroll
    for (int m = 0; m < 4; ++m)
        #pragma unroll
        for (int n = 0; n < 2; ++n)
            #pragma unroll
            for (int r = 0; r < 4; ++r) {
                int row = wr * 64 + m * 16 + lk * 4 + r;
                int col = wc * 32 + n * 16 + lrow;
                __bf16 b = (__bf16)acc[m][n][r];
                simsb[row * SIMSTR + col] = *(unsigned short*)&b;
            }
    __syncthreads();

    // fused scan: 2 threads per row, 32 cols each; labels straight from global
    {
        const int row = t >> 1, half = t & 1;
        const int myc = tcol[row];
        const int4* lab4 = (const int4*)(trow + j0 + half * 32);
        float top[NEG_TOPK];
        #pragma unroll
        for (int q = 0; q < NEG_TOPK; ++q) top[q] = -INFINITY;
        float pos = 0.f;
        #pragma unroll
        for (int j = 0; j < 4; ++j) {
            bf16x8 v8 = *(const bf16x8*)(&simsb[row * SIMSTR + half * 32 + j * 8]);
            int4 l1 = lab4[2 * j], l2 = lab4[2 * j + 1];
            int lab[8] = {l1.x, l1.y, l1.z, l1.w, l2.x, l2.y, l2.z, l2.w};
            #pragma unroll
            for (int e = 0; e < 8; ++e) {
                float s = (float)v8[e];
                bool same = (lab[e] == myc);
                pos += (same && s < 0.99999f) ? (1.f - s) : 0.f;
                topk_ins(top, same ? -INFINITY : s);
            }
        }
        // pair-merge via buf1 region (free now)
        float* mtop = (float*)(smem + BUF);            // [512][10]
        float* mpos = (float*)(smem + BUF + 20480);    // [512]
        #pragma unroll
        for (int q = 0; q < NEG_TOPK; ++q) mtop[t * NEG_TOPK + q] = top[q];
        mpos[t] = pos;
        __syncthreads();
        if (half == 0) {
            const float* ot = &mtop[(t + 1) * NEG_TOPK];
            #pragma unroll
            for (int q = 0; q < NEG_TOPK; ++q) topk_ins(top, ot[q]);
            float post = pos + mpos[t + 1];
            float* dst = part_topk + ((size_t)row * gridDim.x + mb) * NEG_TOPK;
            #pragma unroll
            for (int q = 0; q < NEG_TOPK; ++q) dst[q] = top[q];
            pos_part[(size_t)row * gridDim.x + mb] = post;
        }
    }
}

// Pass 2: one block per row. Merge nch*10 candidates -> top-10, sum finite;
// reduce pos partials; row_tot[i] = pos + neg.
__global__ __launch_bounds__(256) void cl_pass2(
    const float* __restrict__ part_topk,
    const float* __restrict__ pos_part,
    float* __restrict__ row_tot,
    int nch)
{
    const int i = blockIdx.x;
    const int t = threadIdx.x;
    __shared__ float stop[256][NEG_TOPK];
    __shared__ float stop2[32][NEG_TOPK];
    __shared__ float red[256];

    const int n = nch * NEG_TOPK;
    const float* src = part_topk + (size_t)i * n;
    float top[NEG_TOPK];
    #pragma unroll
    for (int q = 0; q < NEG_TOPK; ++q) top[q] = -INFINITY;
    for (int idx = t; idx < n; idx += 256) topk_ins(top, src[idx]);
    #pragma unroll
    for (int q = 0; q < NEG_TOPK; ++q) stop[t][q] = top[q];

    float pos = 0.0f;
    const float* psrc = pos_part + (size_t)i * nch;
    for (int idx = t; idx < nch; idx += 256) pos += psrc[idx];
    red[t] = pos;
    __syncthreads();

    for (int s2 = 128; s2 >= 1; s2 >>= 1) {
        if (t < s2) red[t] += red[t + s2];
        __syncthreads();
    }

    if (t < 32) {
        float m[NEG_TOPK];
        #pragma unroll
        for (int q = 0; q < NEG_TOPK; ++q) m[q] = -INFINITY;
        for (int l = 0; l < 8; ++l)
            #pragma unroll
            for (int q = 0; q < NEG_TOPK; ++q) topk_ins(m, stop[t * 8 + l][q]);
        #pragma unroll
        for (int q = 0; q < NEG_TOPK; ++q) stop2[t][q] = m[q];
    }
    __syncthreads();

    if (t == 0) {
        float m[NEG_TOPK];
        #pragma unroll
        for (int q = 0; q < NEG_TOPK; ++q) m[q] = -INFINITY;
        for (int l = 0; l < 32; ++l)
            #pragma unroll
            for (int q = 0; q < NEG_TOPK; ++q) topk_ins(m, stop2[l][q]);
        float neg = 0.0f;
        #pragma unroll
        for (int q = 0; q < NEG_TOPK; ++q)
            if (isfinite(m[q])) neg += m[q];
        row_tot[i] = neg + red[0];
    }
}

// Pass 3: mean over rows.
__global__ __launch_bounds__(256) void cl_pass3(
    const float* __restrict__ row_tot, float* __restrict__ out, int Bn)
{
    __shared__ float red[256];
    const int t = threadIdx.x;
    float v = 0.0f;
    for (int idx = t; idx < Bn; idx += 256) v += row_tot[idx];
    red[t] = v;
    __syncthreads();
    for (int s2 = 128; s2 >= 1; s2 >>= 1) {
        if (t < s2) red[t] += red[t + s2];
        __syncthreads();
    }
    if (t == 0) out[0] = red[0] / (float)Bn;
}

extern "C" void kernel_launch(void* const* d_in, const int* in_sizes, int n_in,
                              void* d_out, int out_size, void* d_ws, size_t ws_size,
                              hipStream_t stream)
{
    const float* A    = (const float*)d_in[0];  // inputs_col [B,D]
    const int*   tcol = (const int*)d_in[1];    // targets_col [B]
    const float* Bm   = (const float*)d_in[2];  // inputs_row [M,D]
    const int*   trow = (const int*)d_in[3];    // target_row [M]
    float* out = (float*)d_out;

    const int Bn = in_sizes[1];          // 256
    const int M  = in_sizes[3];          // 65536
    const int D  = in_sizes[0] / Bn;     // 512
    const int numMB = M / MT;            // 1024 blocks = chunks
    const int nch = numMB;

    char* A_swz = (char*)d_ws;                                    // 256 KB
    float* part_topk = (float*)(A_swz + 8 * ABYTES);              // B*nch*10
    float* pos_part  = part_topk + (size_t)Bn * nch * NEG_TOPK;   // B*nch
    float* row_tot   = pos_part + (size_t)Bn * nch;               // B

    cl_pass0<<<128, 256, 0, stream>>>(A, A_swz, D);
    cl_pass1<<<numMB, 512, 0, stream>>>(A_swz, Bm, tcol, trow,
                                        part_topk, pos_part, D);
    cl_pass2<<<Bn, 256, 0, stream>>>(part_topk, pos_part, row_tot, nch);
    cl_pass3<<<1, 256, 0, stream>>>(row_tot, out, Bn);
}